// Round 1
// baseline (210.133 us; speedup 1.0000x reference)
//
#include <hip/hip_runtime.h>
#include <math.h>

// ---- constants ----
#define SCALE_INV 20.0f
// exp(d/scale) = exp2(d * SCALE_INV * log2(e))
#define EXPK 28.853900817779268f

typedef __bf16 bf16x8 __attribute__((ext_vector_type(8)));
typedef float  f32x4  __attribute__((ext_vector_type(4)));

// ---------------------------------------------------------------------------
// 1. zero x accumulator + loss accumulators
// ---------------------------------------------------------------------------
__global__ void k_zero(float* __restrict__ x, float* __restrict__ accs) {
  int idx = blockIdx.x * blockDim.x + threadIdx.x;
  for (int i = idx; i < 8192 * 128; i += gridDim.x * blockDim.x) x[i] = 0.0f;
  if (idx < 2) accs[idx] = 0.0f;
}

// ---------------------------------------------------------------------------
// 2. head GEMM: x[p][h] += sum_k e[p][k]*w[h][k], split-K=4, fp32 vector
//    grid (128 row-tiles of 64, 4 k-splits), 256 threads
// ---------------------------------------------------------------------------
__global__ __launch_bounds__(256) void k_headgemm(const float* __restrict__ e,
                                                  const float* __restrict__ w,
                                                  float* __restrict__ x) {
  __shared__ float Ea[64 * 33];
  __shared__ float Wc[128 * 33];
  const int t  = threadIdx.x;
  const int rt = blockIdx.x;   // row tile 0..127
  const int k0 = blockIdx.y * 192;
  const int tx = t & 31;       // h base (h = tx + 32j)
  const int ty = t >> 5;       // r base (r = ty + 8i)
  float acc[8][4];
  for (int i = 0; i < 8; i++)
    for (int j = 0; j < 4; j++) acc[i][j] = 0.0f;

  for (int kc = 0; kc < 6; kc++) {
    int kb = k0 + kc * 32;
    for (int it = 0; it < 8; it++) {          // stage Ea 64x32
      int flat = t + it * 256;
      int r = flat >> 5, kk = flat & 31;
      Ea[r * 33 + kk] = e[(rt * 64 + r) * 768 + kb + kk];
    }
    for (int it = 0; it < 16; it++) {         // stage Wc 128x32
      int flat = t + it * 256;
      int h = flat >> 5, kk = flat & 31;
      Wc[h * 33 + kk] = w[h * 768 + kb + kk];
    }
    __syncthreads();
    for (int kk = 0; kk < 32; kk++) {
      float a[8], b[4];
      for (int i = 0; i < 8; i++) a[i] = Ea[(ty + 8 * i) * 33 + kk];
      for (int j = 0; j < 4; j++) b[j] = Wc[(tx + 32 * j) * 33 + kk];
      for (int i = 0; i < 8; i++)
        for (int j = 0; j < 4; j++) acc[i][j] += a[i] * b[j];
    }
    __syncthreads();
  }
  for (int i = 0; i < 8; i++)
    for (int j = 0; j < 4; j++)
      atomicAdd(&x[(rt * 64 + ty + 8 * i) * 128 + tx + 32 * j], acc[i][j]);
}

// ---------------------------------------------------------------------------
// 3. bias + row l2norm; writes nx fp32 (in place) and bf16 copy
// ---------------------------------------------------------------------------
__global__ __launch_bounds__(128) void k_norm(const float* x,
                                              const float* __restrict__ hb,
                                              float* nx,
                                              __bf16* __restrict__ nxb) {
  __shared__ float wsum[2];
  const int p = blockIdx.x, t = threadIdx.x;
  float v = x[p * 128 + t] + hb[t];
  float s = v * v;
  for (int off = 32; off; off >>= 1) s += __shfl_xor(s, off, 64);
  if ((t & 63) == 0) wsum[t >> 6] = s;
  __syncthreads();
  float ss  = wsum[0] + wsum[1];
  float inv = 1.0f / fmaxf(sqrtf(ss), 1e-12f);
  float nv  = v * inv;
  nx[p * 128 + t]  = nv;
  nxb[p * 128 + t] = (__bf16)nv;
}

// ---------------------------------------------------------------------------
// 4. l2norm proto rows
// ---------------------------------------------------------------------------
__global__ __launch_bounds__(128) void k_protonorm(const float* __restrict__ proto,
                                                   float* __restrict__ npr) {
  __shared__ float wsum[2];
  const int k = blockIdx.x, t = threadIdx.x;
  float v = proto[k * 128 + t];
  float s = v * v;
  for (int off = 32; off; off >>= 1) s += __shfl_xor(s, off, 64);
  if ((t & 63) == 0) wsum[t >> 6] = s;
  __syncthreads();
  float inv = 1.0f / fmaxf(sqrtf(wsum[0] + wsum[1]), 1e-12f);
  npr[k * 128 + t] = v * inv;
}

// ---------------------------------------------------------------------------
// 5. proto contrastive term. grid 256 = (class 64) x (n-split 4), 256 thr.
//    One wave handles 8 n's; lane k computes dot(nx[c,n], nproto[k]).
// ---------------------------------------------------------------------------
__global__ __launch_bounds__(256) void k_protoloss(const float* __restrict__ nx,
                                                   const float* __restrict__ npr,
                                                   float* __restrict__ accs) {
  __shared__ float npl[64 * 129];
  __shared__ float nxr[32 * 129];
  const int t   = threadIdx.x;
  const int cls = blockIdx.x >> 2;
  const int n0  = (blockIdx.x & 3) * 32;
  for (int it = 0; it < 32; it++) {
    int flat = t + it * 256; int k = flat >> 7, j = flat & 127;
    npl[k * 129 + j] = npr[k * 128 + j];
  }
  for (int it = 0; it < 16; it++) {
    int flat = t + it * 256; int r = flat >> 7, j = flat & 127;
    nxr[r * 129 + j] = nx[(cls * 128 + n0 + r) * 128 + j];
  }
  __syncthreads();
  const int w = t >> 6, lane = t & 63;
  float wacc = 0.0f;
  for (int nn = 0; nn < 8; nn++) {
    int nl = w * 8 + nn;
    const float* xr = &nxr[nl * 129];
    const float* pk = &npl[lane * 129];
    float d = 0.0f;
    for (int j = 0; j < 128; j++) d += xr[j] * pk[j];
    float tot = exp2f(d * EXPK);
    for (int off = 32; off; off >>= 1) tot += __shfl_xor(tot, off, 64);
    float dpos = __shfl(d, cls, 64);
    wacc += logf(tot) - dpos * SCALE_INV;
  }
  if (lane == 0) atomicAdd(&accs[0], wacc);
}

// ---------------------------------------------------------------------------
// 6. off-class colsum pass (the big one). bf16 MFMA 16x16x32.
//    grid (64 col-classes, 8 row-splits), 256 thr, 128x128 tiles,
//    diagonal class blocks skipped (exact cancellation with pass 2).
// ---------------------------------------------------------------------------
__global__ __launch_bounds__(256) void k_colsum(const __bf16* __restrict__ nxb,
                                                float* __restrict__ cspart) {
  __shared__ __bf16 At[128 * 136];
  __shared__ __bf16 Bt[128 * 136];
  __shared__ float  colpart[4 * 128];
  const int t    = threadIdx.x;
  const int ct   = blockIdx.x;   // class / col tile
  const int rs   = blockIdx.y;   // row split
  const int w    = t >> 6, lane = t & 63;
  const int quad = lane >> 4, lrow = lane & 15;

  // stage Bt (column rows ct*128..+128) once
  for (int it = 0; it < 8; it++) {
    int flat = t + it * 256;
    int r = flat >> 4, seg = flat & 15;
    *(bf16x8*)&Bt[r * 136 + seg * 8] =
        *(const bf16x8*)&nxb[(ct * 128 + r) * 128 + seg * 8];
  }
  float colacc[8];
  for (int j = 0; j < 8; j++) colacc[j] = 0.0f;
  __syncthreads();

  for (int c8 = 0; c8 < 8; c8++) {
    int row0 = rs * 1024 + c8 * 128;
    if (row0 == ct * 128) continue;  // skip diagonal class block (uniform)
    for (int it = 0; it < 8; it++) {
      int flat = t + it * 256;
      int r = flat >> 4, seg = flat & 15;
      *(bf16x8*)&At[r * 136 + seg * 8] =
          *(const bf16x8*)&nxb[(row0 + r) * 128 + seg * 8];
    }
    __syncthreads();

    f32x4 acc[2][8];
    f32x4 zero = {0.0f, 0.0f, 0.0f, 0.0f};
    for (int i = 0; i < 2; i++)
      for (int j = 0; j < 8; j++) acc[i][j] = zero;

    for (int kc = 0; kc < 4; kc++) {
      bf16x8 a0 = *(const bf16x8*)&At[(w * 32 + lrow) * 136 + kc * 32 + quad * 8];
      bf16x8 a1 = *(const bf16x8*)&At[(w * 32 + 16 + lrow) * 136 + kc * 32 + quad * 8];
      for (int j = 0; j < 8; j++) {
        bf16x8 b = *(const bf16x8*)&Bt[(j * 16 + lrow) * 136 + kc * 32 + quad * 8];
        acc[0][j] = __builtin_amdgcn_mfma_f32_16x16x32_bf16(a0, b, acc[0][j], 0, 0, 0);
        acc[1][j] = __builtin_amdgcn_mfma_f32_16x16x32_bf16(a1, b, acc[1][j], 0, 0, 0);
      }
    }
    for (int i = 0; i < 2; i++)
      for (int j = 0; j < 8; j++)
        for (int r = 0; r < 4; r++)
          colacc[j] += exp2f(acc[i][j][r] * EXPK);
    __syncthreads();
  }

  // reduce across quads then waves; col = j*16 + (lane&15)
  for (int j = 0; j < 8; j++) {
    float v = colacc[j];
    v += __shfl_xor(v, 16, 64);
    v += __shfl_xor(v, 32, 64);
    if (lane < 16) colpart[w * 128 + j * 16 + lane] = v;
  }
  __syncthreads();
  if (t < 128) {
    float s = colpart[t] + colpart[128 + t] + colpart[256 + t] + colpart[384 + t];
    cspart[rs * 8192 + ct * 128 + t] = s;
  }
}

// ---------------------------------------------------------------------------
// 7. instance loss pass 2: per q, fp32 in-class dots + log1p terms.
//    grid 512 = (class 64) x (q-split 8), 256 thr.
// ---------------------------------------------------------------------------
__global__ __launch_bounds__(256) void k_instloss(const float* __restrict__ nx,
                                                  const float* __restrict__ cspart,
                                                  float* __restrict__ accs) {
  __shared__ float blk[128 * 129];
  const int t   = threadIdx.x;
  const int cls = blockIdx.x >> 3;
  const int qs  = blockIdx.x & 7;
  for (int it = 0; it < 64; it++) {
    int flat = t + it * 256; int r = flat >> 7, j = flat & 127;
    blk[r * 129 + j] = nx[(cls * 128 + r) * 128 + j];
  }
  __syncthreads();
  const int w = t >> 6, lane = t & 63;
  float wacc = 0.0f;
  for (int qi = 0; qi < 4; qi++) {
    int nl = qs * 16 + w * 4 + qi;
    int q  = cls * 128 + nl;
    float neg = 0.0f;
    for (int s = 0; s < 8; s++) neg += cspart[s * 8192 + q];
    const float* xq  = &blk[nl * 129];
    const float* xm1 = &blk[lane * 129];
    const float* xm2 = &blk[(lane + 64) * 129];
    float d1 = 0.0f, d2 = 0.0f;
    for (int j = 0; j < 128; j++) {
      float qv = xq[j];
      d1 += xm1[j] * qv;
      d2 += xm2[j] * qv;
    }
    float t1 = log1pf(neg * exp2f(-d1 * EXPK));
    float t2 = log1pf(neg * exp2f(-d2 * EXPK));
    float tv = t1 + t2;
    for (int off = 32; off; off >>= 1) tv += __shfl_xor(tv, off, 64);
    if (lane == 0) wacc += tv;
  }
  if (lane == 0) atomicAdd(&accs[1], wacc);
}

// ---------------------------------------------------------------------------
// 8. finalize
// ---------------------------------------------------------------------------
__global__ void k_final(const float* __restrict__ accs, float* __restrict__ out) {
  out[0] = accs[0] * (1.0f / 524288.0f) + accs[1] * (1.0f / 67108864.0f);
}

// ---------------------------------------------------------------------------
extern "C" void kernel_launch(void* const* d_in, const int* in_sizes, int n_in,
                              void* d_out, int out_size, void* d_ws, size_t ws_size,
                              hipStream_t stream) {
  const float* e  = (const float*)d_in[0];   // embeds [64,128,768]
  const float* w  = (const float*)d_in[1];   // head_w [128,768]
  const float* hb = (const float*)d_in[2];   // head_b [128]
  const float* pr = (const float*)d_in[3];   // proto  [64,128]
  char* ws = (char*)d_ws;
  float*  x      = (float*)ws;                          // 4 MB (becomes nx)
  __bf16* nxb    = (__bf16*)(ws + (4 << 20));           // 2 MB
  float*  npr    = (float*)(ws + (6 << 20));            // 32 KB
  float*  cspart = (float*)(ws + (6 << 20) + (64 << 10));   // 256 KB
  float*  accs   = (float*)(ws + (6 << 20) + (512 << 10));  // 8 B
  float*  out    = (float*)d_out;

  k_zero<<<1024, 256, 0, stream>>>(x, accs);
  k_headgemm<<<dim3(128, 4), 256, 0, stream>>>(e, w, x);
  k_norm<<<8192, 128, 0, stream>>>(x, hb, x, nxb);
  k_protonorm<<<64, 128, 0, stream>>>(pr, npr);
  k_protoloss<<<256, 256, 0, stream>>>(x, npr, accs);
  k_colsum<<<dim3(64, 8), 256, 0, stream>>>(nxb, cspart);
  k_instloss<<<512, 256, 0, stream>>>(x, cspart, accs);
  k_final<<<1, 1, 0, stream>>>(accs, out);
}

// Round 2
// 156.031 us; speedup vs baseline: 1.3467x; 1.3467x over previous
//
#include <hip/hip_runtime.h>
#include <math.h>

#define SCALE_INV 20.0f
#define EXPK 28.853900817779268f   // SCALE_INV * log2(e)
#define LN2F 0.6931471805599453f

typedef __bf16 bf16x8 __attribute__((ext_vector_type(8)));
typedef float  f32x4  __attribute__((ext_vector_type(4)));

// ---------------------------------------------------------------------------
// 1. fused head GEMM + bias + l2norm -> nxb (bf16). grid 256 x 256 thr.
//    x[r][h] = sum_k e[r][k] * w[h][k];  nx = l2norm(x + b); per block 32 rows.
//    bf16 MFMA 16x16x32, convert-on-stage, register-prefetch pipeline.
// ---------------------------------------------------------------------------
__global__ __launch_bounds__(256) void k_headnorm(const float* __restrict__ e,
                                                  const float* __restrict__ w,
                                                  const float* __restrict__ hb,
                                                  __bf16* __restrict__ nxb) {
  __shared__ __bf16 Ab[32 * 72];    // 32 rows x 64 k (pad 72)
  __shared__ __bf16 Bb[128 * 72];   // 128 h  x 64 k
  __shared__ float  xt[32 * 132];   // output tile for norm
  __shared__ float  hbl[128];
  const int t  = threadIdx.x;
  const int rt = blockIdx.x;        // 32-row tile
  if (t < 128) hbl[t] = hb[t];

  const int arow = t >> 3, akoff = (t & 7) * 8;   // A: 8 floats/thread
  const int brow = t >> 1, bkoff = (t & 1) * 32;  // B: 32 floats/thread
  float4 ar[2], br[8];
  {
    const float* p = &e[(rt * 32 + arow) * 768 + akoff];
    ar[0] = *(const float4*)p; ar[1] = *(const float4*)(p + 4);
    const float* q = &w[brow * 768 + bkoff];
    for (int i = 0; i < 8; i++) br[i] = *(const float4*)(q + 4 * i);
  }

  const int wv = t >> 6, lane = t & 63;
  const int quad = lane >> 4, lrow = lane & 15;
  const int rb = wv & 1, cb = wv >> 1;   // rows rb*16, cols cb*64
  f32x4 acc[4];
  f32x4 zero = {0.f, 0.f, 0.f, 0.f};
  for (int j = 0; j < 4; j++) acc[j] = zero;

  for (int it = 0; it < 12; it++) {
    // convert regs -> LDS bf16
    {
      __bf16 ta[8];
      const float* f = (const float*)ar;
      for (int i = 0; i < 8; i++) ta[i] = (__bf16)f[i];
      *(bf16x8*)&Ab[arow * 72 + akoff] = *(bf16x8*)ta;
      const float* g = (const float*)br;
      for (int seg = 0; seg < 4; seg++) {
        __bf16 tb[8];
        for (int i = 0; i < 8; i++) tb[i] = (__bf16)g[seg * 8 + i];
        *(bf16x8*)&Bb[brow * 72 + bkoff + seg * 8] = *(bf16x8*)tb;
      }
    }
    __syncthreads();
    if (it < 11) {  // prefetch next chunk (overlaps MFMA below)
      int kb = (it + 1) * 64;
      const float* p = &e[(rt * 32 + arow) * 768 + kb + akoff];
      ar[0] = *(const float4*)p; ar[1] = *(const float4*)(p + 4);
      const float* q = &w[brow * 768 + kb + bkoff];
      for (int i = 0; i < 8; i++) br[i] = *(const float4*)(q + 4 * i);
    }
    for (int kc = 0; kc < 2; kc++) {
      bf16x8 a = *(const bf16x8*)&Ab[(rb * 16 + lrow) * 72 + kc * 32 + quad * 8];
      for (int j = 0; j < 4; j++) {
        bf16x8 b = *(const bf16x8*)&Bb[(cb * 64 + j * 16 + lrow) * 72 + kc * 32 + quad * 8];
        acc[j] = __builtin_amdgcn_mfma_f32_16x16x32_bf16(a, b, acc[j], 0, 0, 0);
      }
    }
    __syncthreads();
  }

  // epilogue: acc -> xt (+bias), then row l2norm, write bf16
  for (int j = 0; j < 4; j++)
    for (int r = 0; r < 4; r++) {
      int row = rb * 16 + quad * 4 + r;
      int col = cb * 64 + j * 16 + lrow;
      xt[row * 132 + col] = acc[j][r] + hbl[col];
    }
  __syncthreads();
  {
    int row = t >> 3, c0 = (t & 7) * 16;
    float v[16];
    float s = 0.0f;
    for (int i = 0; i < 4; i++) {
      float4 f = *(const float4*)&xt[row * 132 + c0 + i * 4];
      v[i * 4] = f.x; v[i * 4 + 1] = f.y; v[i * 4 + 2] = f.z; v[i * 4 + 3] = f.w;
    }
    for (int i = 0; i < 16; i++) s += v[i] * v[i];
    s += __shfl_xor(s, 1, 64);
    s += __shfl_xor(s, 2, 64);
    s += __shfl_xor(s, 4, 64);
    float inv = 1.0f / fmaxf(sqrtf(s), 1e-12f);
    __bf16 o[16];
    for (int i = 0; i < 16; i++) o[i] = (__bf16)(v[i] * inv);
    __bf16* dst = &nxb[(rt * 32 + row) * 128 + c0];
    *(bf16x8*)dst       = *(bf16x8*)o;
    *(bf16x8*)(dst + 8) = *(bf16x8*)(o + 8);
  }
}

// ---------------------------------------------------------------------------
// 2. l2norm proto rows -> bf16; also zero loss accumulators
// ---------------------------------------------------------------------------
__global__ __launch_bounds__(128) void k_protonorm(const float* __restrict__ proto,
                                                   __bf16* __restrict__ nprb,
                                                   float* __restrict__ accs) {
  __shared__ float wsum[2];
  const int k = blockIdx.x, t = threadIdx.x;
  float v = proto[k * 128 + t];
  float s = v * v;
  for (int off = 32; off; off >>= 1) s += __shfl_xor(s, off, 64);
  if ((t & 63) == 0) wsum[t >> 6] = s;
  __syncthreads();
  float inv = 1.0f / fmaxf(sqrtf(wsum[0] + wsum[1]), 1e-12f);
  nprb[k * 128 + t] = (__bf16)(v * inv);
  if (k == 0 && t < 2) accs[t] = 0.0f;
}

// ---------------------------------------------------------------------------
// 3. proto contrastive term via MFMA. grid 64 (one class), 256 thr.
//    D[m][c'] = nx[cls,m] . nproto[c'];  loss0 += log(sum_c' exp(D*k)) - D[m][cls]*k
// ---------------------------------------------------------------------------
__global__ __launch_bounds__(256) void k_protoloss2(const __bf16* __restrict__ nxb,
                                                    const __bf16* __restrict__ nprb,
                                                    float* __restrict__ accs) {
  __shared__ __bf16 Xt[128 * 136];
  __shared__ __bf16 Pt[64 * 136];
  const int t = threadIdx.x, cls = blockIdx.x;
  for (int it = 0; it < 8; it++) {
    int flat = t + it * 256;
    int r = flat >> 4, seg = flat & 15;
    *(bf16x8*)&Xt[r * 136 + seg * 8] =
        *(const bf16x8*)&nxb[(cls * 128 + r) * 128 + seg * 8];
  }
  for (int it = 0; it < 4; it++) {
    int flat = t + it * 256;
    int r = flat >> 4, seg = flat & 15;
    *(bf16x8*)&Pt[r * 136 + seg * 8] =
        *(const bf16x8*)&nprb[r * 128 + seg * 8];
  }
  __syncthreads();

  const int wv = t >> 6, lane = t & 63;
  const int quad = lane >> 4, lrow = lane & 15;
  f32x4 acc[2][4];
  f32x4 zero = {0.f, 0.f, 0.f, 0.f};
  for (int i = 0; i < 2; i++)
    for (int j = 0; j < 4; j++) acc[i][j] = zero;

  for (int kc = 0; kc < 4; kc++) {
    bf16x8 a0 = *(const bf16x8*)&Xt[(wv * 32 + lrow) * 136 + kc * 32 + quad * 8];
    bf16x8 a1 = *(const bf16x8*)&Xt[(wv * 32 + 16 + lrow) * 136 + kc * 32 + quad * 8];
    for (int j = 0; j < 4; j++) {
      bf16x8 b = *(const bf16x8*)&Pt[(j * 16 + lrow) * 136 + kc * 32 + quad * 8];
      acc[0][j] = __builtin_amdgcn_mfma_f32_16x16x32_bf16(a0, b, acc[0][j], 0, 0, 0);
      acc[1][j] = __builtin_amdgcn_mfma_f32_16x16x32_bf16(a1, b, acc[1][j], 0, 0, 0);
    }
  }

  const int jc = cls >> 4, colc = cls & 15;
  float wacc = 0.0f;
  for (int i = 0; i < 2; i++) {
    for (int r = 0; r < 4; r++) {
      float tot = 0.0f;
      for (int j = 0; j < 4; j++) tot += exp2f(acc[i][j][r] * EXPK);
      tot += __shfl_xor(tot, 1, 64);
      tot += __shfl_xor(tot, 2, 64);
      tot += __shfl_xor(tot, 4, 64);
      tot += __shfl_xor(tot, 8, 64);
      if (lrow == 0) wacc += logf(tot);
    }
    if (lrow == colc) {
      float sd = 0.0f;
      switch (jc) {
        case 0: for (int r = 0; r < 4; r++) sd += acc[i][0][r]; break;
        case 1: for (int r = 0; r < 4; r++) sd += acc[i][1][r]; break;
        case 2: for (int r = 0; r < 4; r++) sd += acc[i][2][r]; break;
        default: for (int r = 0; r < 4; r++) sd += acc[i][3][r]; break;
      }
      wacc -= SCALE_INV * sd;
    }
  }
  for (int off = 32; off; off >>= 1) wacc += __shfl_xor(wacc, off, 64);
  if (lane == 0) atomicAdd(&accs[0], wacc);
}

// ---------------------------------------------------------------------------
// 4. off-class colsum pass (unchanged, verified). grid (64, 8), 256 thr.
// ---------------------------------------------------------------------------
__global__ __launch_bounds__(256) void k_colsum(const __bf16* __restrict__ nxb,
                                                float* __restrict__ cspart) {
  __shared__ __bf16 At[128 * 136];
  __shared__ __bf16 Bt[128 * 136];
  __shared__ float  colpart[4 * 128];
  const int t    = threadIdx.x;
  const int ct   = blockIdx.x;
  const int rs   = blockIdx.y;
  const int w    = t >> 6, lane = t & 63;
  const int quad = lane >> 4, lrow = lane & 15;

  for (int it = 0; it < 8; it++) {
    int flat = t + it * 256;
    int r = flat >> 4, seg = flat & 15;
    *(bf16x8*)&Bt[r * 136 + seg * 8] =
        *(const bf16x8*)&nxb[(ct * 128 + r) * 128 + seg * 8];
  }
  float colacc[8];
  for (int j = 0; j < 8; j++) colacc[j] = 0.0f;
  __syncthreads();

  for (int c8 = 0; c8 < 8; c8++) {
    int row0 = rs * 1024 + c8 * 128;
    if (row0 == ct * 128) continue;  // diagonal class block cancels analytically
    for (int it = 0; it < 8; it++) {
      int flat = t + it * 256;
      int r = flat >> 4, seg = flat & 15;
      *(bf16x8*)&At[r * 136 + seg * 8] =
          *(const bf16x8*)&nxb[(row0 + r) * 128 + seg * 8];
    }
    __syncthreads();

    f32x4 acc[2][8];
    f32x4 zero = {0.0f, 0.0f, 0.0f, 0.0f};
    for (int i = 0; i < 2; i++)
      for (int j = 0; j < 8; j++) acc[i][j] = zero;

    for (int kc = 0; kc < 4; kc++) {
      bf16x8 a0 = *(const bf16x8*)&At[(w * 32 + lrow) * 136 + kc * 32 + quad * 8];
      bf16x8 a1 = *(const bf16x8*)&At[(w * 32 + 16 + lrow) * 136 + kc * 32 + quad * 8];
      for (int j = 0; j < 8; j++) {
        bf16x8 b = *(const bf16x8*)&Bt[(j * 16 + lrow) * 136 + kc * 32 + quad * 8];
        acc[0][j] = __builtin_amdgcn_mfma_f32_16x16x32_bf16(a0, b, acc[0][j], 0, 0, 0);
        acc[1][j] = __builtin_amdgcn_mfma_f32_16x16x32_bf16(a1, b, acc[1][j], 0, 0, 0);
      }
    }
    for (int i = 0; i < 2; i++)
      for (int j = 0; j < 8; j++)
        for (int r = 0; r < 4; r++)
          colacc[j] += exp2f(acc[i][j][r] * EXPK);
    __syncthreads();
  }

  for (int j = 0; j < 8; j++) {
    float v = colacc[j];
    v += __shfl_xor(v, 16, 64);
    v += __shfl_xor(v, 32, 64);
    if (lane < 16) colpart[w * 128 + j * 16 + lane] = v;
  }
  __syncthreads();
  if (t < 128) {
    float s = colpart[t] + colpart[128 + t] + colpart[256 + t] + colpart[384 + t];
    cspart[rs * 8192 + ct * 128 + t] = s;
  }
}

// ---------------------------------------------------------------------------
// 5. instance loss via MFMA. grid 64 (one class), 256 thr.
//    D[m][n] in-class dots; term = log1p(neg[n] * exp(-D*k)).
// ---------------------------------------------------------------------------
__global__ __launch_bounds__(256) void k_instcls(const __bf16* __restrict__ nxb,
                                                 const float* __restrict__ cspart,
                                                 float* __restrict__ accs) {
  __shared__ __bf16 Bt[128 * 136];
  __shared__ float  negl[128];
  const int t = threadIdx.x, cls = blockIdx.x;
  for (int it = 0; it < 8; it++) {
    int flat = t + it * 256;
    int r = flat >> 4, seg = flat & 15;
    *(bf16x8*)&Bt[r * 136 + seg * 8] =
        *(const bf16x8*)&nxb[(cls * 128 + r) * 128 + seg * 8];
  }
  if (t < 128) {
    float s = 0.0f;
    for (int s8 = 0; s8 < 8; s8++) s += cspart[s8 * 8192 + cls * 128 + t];
    negl[t] = s;
  }
  __syncthreads();

  const int wv = t >> 6, lane = t & 63;
  const int quad = lane >> 4, lrow = lane & 15;
  f32x4 acc[2][8];
  f32x4 zero = {0.f, 0.f, 0.f, 0.f};
  for (int i = 0; i < 2; i++)
    for (int j = 0; j < 8; j++) acc[i][j] = zero;

  for (int kc = 0; kc < 4; kc++) {
    bf16x8 a0 = *(const bf16x8*)&Bt[(wv * 32 + lrow) * 136 + kc * 32 + quad * 8];
    bf16x8 a1 = *(const bf16x8*)&Bt[(wv * 32 + 16 + lrow) * 136 + kc * 32 + quad * 8];
    for (int j = 0; j < 8; j++) {
      bf16x8 b = *(const bf16x8*)&Bt[(j * 16 + lrow) * 136 + kc * 32 + quad * 8];
      acc[0][j] = __builtin_amdgcn_mfma_f32_16x16x32_bf16(a0, b, acc[0][j], 0, 0, 0);
      acc[1][j] = __builtin_amdgcn_mfma_f32_16x16x32_bf16(a1, b, acc[1][j], 0, 0, 0);
    }
  }

  float wacc = 0.0f;
  for (int j = 0; j < 8; j++) {
    float ng = negl[j * 16 + lrow];
    for (int i = 0; i < 2; i++)
      for (int r = 0; r < 4; r++)
        wacc += log1pf(ng * exp2f(-acc[i][j][r] * EXPK));
  }
  for (int off = 32; off; off >>= 1) wacc += __shfl_xor(wacc, off, 64);
  if (lane == 0) atomicAdd(&accs[1], wacc);
}

// ---------------------------------------------------------------------------
// 6. finalize
// ---------------------------------------------------------------------------
__global__ void k_final(const float* __restrict__ accs, float* __restrict__ out) {
  out[0] = accs[0] * (1.0f / 524288.0f) + accs[1] * (1.0f / 67108864.0f);
}

// ---------------------------------------------------------------------------
extern "C" void kernel_launch(void* const* d_in, const int* in_sizes, int n_in,
                              void* d_out, int out_size, void* d_ws, size_t ws_size,
                              hipStream_t stream) {
  const float* e  = (const float*)d_in[0];   // embeds [64,128,768]
  const float* w  = (const float*)d_in[1];   // head_w [128,768]
  const float* hb = (const float*)d_in[2];   // head_b [128]
  const float* pr = (const float*)d_in[3];   // proto  [64,128]
  char* ws = (char*)d_ws;
  __bf16* nxb    = (__bf16*)ws;                          // 2 MB
  __bf16* nprb   = (__bf16*)(ws + (2 << 20));            // 16 KB
  float*  cspart = (float*)(ws + (2 << 20) + (64 << 10));   // 256 KB
  float*  accs   = (float*)(ws + (2 << 20) + (512 << 10));  // 8 B
  float*  out    = (float*)d_out;

  k_headnorm<<<256, 256, 0, stream>>>(e, w, hb, nxb);
  k_protonorm<<<64, 128, 0, stream>>>(pr, nprb, accs);
  k_protoloss2<<<64, 256, 0, stream>>>(nxb, nprb, accs);
  k_colsum<<<dim3(64, 8), 256, 0, stream>>>(nxb, cspart);
  k_instcls<<<64, 256, 0, stream>>>(nxb, cspart, accs);
  k_final<<<1, 1, 0, stream>>>(accs, out);
}

// Round 3
// 152.057 us; speedup vs baseline: 1.3819x; 1.0261x over previous
//
#include <hip/hip_runtime.h>
#include <math.h>

#define SCALE_INV 20.0f
#define EXPK 28.853900817779268f   // SCALE_INV * log2(e)
#define LN2F 0.6931471805599453f   // SCALE_INV / EXPK

typedef __bf16 bf16x8 __attribute__((ext_vector_type(8)));
typedef float  f32x4  __attribute__((ext_vector_type(4)));

// ---------------------------------------------------------------------------
// 1. prep: w -> bf16 wb; proto -> l2norm, scale by EXPK -> nprE (bf16);
//    zero accs. grid 128 x 256.
// ---------------------------------------------------------------------------
__global__ __launch_bounds__(256) void k_prep(const float* __restrict__ w,
                                              const float* __restrict__ proto,
                                              __bf16* __restrict__ wb,
                                              __bf16* __restrict__ nprE,
                                              float* __restrict__ accs) {
  const int b = blockIdx.x, t = threadIdx.x;
  if (b < 32) {
    // two proto rows per block
    __shared__ float wsum[4];
    const int sub = t >> 7, tt = t & 127, row = b * 2 + sub;
    float v = proto[row * 128 + tt];
    float s = v * v;
    for (int off = 32; off; off >>= 1) s += __shfl_xor(s, off, 64);
    if ((t & 63) == 0) wsum[t >> 6] = s;
    __syncthreads();
    float inv = 1.0f / fmaxf(sqrtf(wsum[sub * 2] + wsum[sub * 2 + 1]), 1e-12f);
    nprE[row * 128 + tt] = (__bf16)(v * inv * EXPK);
    if (b == 0 && t < 4) accs[t] = 0.0f;
  } else {
    int i = (b - 32) * 1024 + t * 4;
    float4 f = *(const float4*)&w[i];
    __bf16 o[4] = {(__bf16)f.x, (__bf16)f.y, (__bf16)f.z, (__bf16)f.w};
    *(float*)&wb[i] = *(float*)o;  // 8B store of 4 bf16
  }
}

// ---------------------------------------------------------------------------
// 2. fused head GEMM + bias + l2norm -> nxb, nxe. grid 256 x 256.
//    32 rows/block, K-chunks of 128, register-prefetch pipeline.
// ---------------------------------------------------------------------------
__global__ __launch_bounds__(256) void k_headnorm(const float* __restrict__ e,
                                                  const __bf16* __restrict__ wb,
                                                  const float* __restrict__ hb,
                                                  __bf16* __restrict__ nxb,
                                                  __bf16* __restrict__ nxe) {
  __shared__ __bf16 Ab[32 * 136];
  __shared__ __bf16 Bb[128 * 136];
  __shared__ float  xt[32 * 132];
  __shared__ float  hbl[128];
  const int t  = threadIdx.x;
  const int rt = blockIdx.x;
  if (t < 128) hbl[t] = hb[t];

  const int arow = t >> 3, akoff = (t & 7) * 16;  // 16 floats of e
  const int brow = t >> 1, bkoff = (t & 1) * 64;  // 64 bf16 of wb
  float4 ar[4];
  bf16x8 brg[8];
  {
    const float* p = &e[(rt * 32 + arow) * 768 + akoff];
    for (int i = 0; i < 4; i++) ar[i] = *(const float4*)(p + 4 * i);
    const __bf16* q = &wb[brow * 768 + bkoff];
    for (int i = 0; i < 8; i++) brg[i] = *(const bf16x8*)(q + 8 * i);
  }

  const int wv = t >> 6, lane = t & 63;
  const int quad = lane >> 4, lrow = lane & 15;
  const int rb = wv & 1, cb = wv >> 1;
  f32x4 acc[4];
  f32x4 zero = {0.f, 0.f, 0.f, 0.f};
  for (int j = 0; j < 4; j++) acc[j] = zero;

  for (int it = 0; it < 6; it++) {
    {
      __bf16 ta[16];
      const float* f = (const float*)ar;
      for (int i = 0; i < 16; i++) ta[i] = (__bf16)f[i];
      *(bf16x8*)&Ab[arow * 136 + akoff]     = *(bf16x8*)ta;
      *(bf16x8*)&Ab[arow * 136 + akoff + 8] = *(bf16x8*)(ta + 8);
      for (int seg = 0; seg < 8; seg++)
        *(bf16x8*)&Bb[brow * 136 + bkoff + seg * 8] = brg[seg];
    }
    __syncthreads();
    if (it < 5) {
      int kb = (it + 1) * 128;
      const float* p = &e[(rt * 32 + arow) * 768 + kb + akoff];
      for (int i = 0; i < 4; i++) ar[i] = *(const float4*)(p + 4 * i);
      const __bf16* q = &wb[brow * 768 + kb + bkoff];
      for (int i = 0; i < 8; i++) brg[i] = *(const bf16x8*)(q + 8 * i);
    }
    for (int kc = 0; kc < 4; kc++) {
      bf16x8 a = *(const bf16x8*)&Ab[(rb * 16 + lrow) * 136 + kc * 32 + quad * 8];
      for (int j = 0; j < 4; j++) {
        bf16x8 b = *(const bf16x8*)&Bb[(cb * 64 + j * 16 + lrow) * 136 + kc * 32 + quad * 8];
        acc[j] = __builtin_amdgcn_mfma_f32_16x16x32_bf16(a, b, acc[j], 0, 0, 0);
      }
    }
    __syncthreads();
  }

  for (int j = 0; j < 4; j++)
    for (int r = 0; r < 4; r++) {
      int row = rb * 16 + quad * 4 + r;
      int col = cb * 64 + j * 16 + lrow;
      xt[row * 132 + col] = acc[j][r] + hbl[col];
    }
  __syncthreads();
  {
    int row = t >> 3, c0 = (t & 7) * 16;
    float v[16];
    float s = 0.0f;
    for (int i = 0; i < 4; i++) {
      float4 f = *(const float4*)&xt[row * 132 + c0 + i * 4];
      v[i * 4] = f.x; v[i * 4 + 1] = f.y; v[i * 4 + 2] = f.z; v[i * 4 + 3] = f.w;
    }
    for (int i = 0; i < 16; i++) s += v[i] * v[i];
    s += __shfl_xor(s, 1, 64);
    s += __shfl_xor(s, 2, 64);
    s += __shfl_xor(s, 4, 64);
    float inv = 1.0f / fmaxf(sqrtf(s), 1e-12f);
    __bf16 o[16], oe[16];
    for (int i = 0; i < 16; i++) {
      float nv = v[i] * inv;
      o[i]  = (__bf16)nv;
      oe[i] = (__bf16)(nv * EXPK);
    }
    __bf16* dst = &nxb[(rt * 32 + row) * 128 + c0];
    *(bf16x8*)dst       = *(bf16x8*)o;
    *(bf16x8*)(dst + 8) = *(bf16x8*)(o + 8);
    __bf16* dse = &nxe[(rt * 32 + row) * 128 + c0];
    *(bf16x8*)dse       = *(bf16x8*)oe;
    *(bf16x8*)(dse + 8) = *(bf16x8*)(oe + 8);
  }
}

// ---------------------------------------------------------------------------
// 3. off-class colsum. grid (64, 8), 256 thr. A=nxb rows, B=nxe cols
//    (prescaled, so epilogue is exp2f(acc) directly). Reg-prefetch pipeline.
// ---------------------------------------------------------------------------
__global__ __launch_bounds__(256) void k_colsum(const __bf16* __restrict__ nxb,
                                                const __bf16* __restrict__ nxe,
                                                float* __restrict__ cspart) {
  __shared__ __bf16 At[128 * 136];
  __shared__ __bf16 Bt[128 * 136];
  __shared__ float  colpart[4 * 128];
  const int t    = threadIdx.x;
  const int ct   = blockIdx.x;
  const int rs   = blockIdx.y;
  const int w    = t >> 6, lane = t & 63;
  const int quad = lane >> 4, lrow = lane & 15;
  const int sr   = t >> 4, sseg = t & 15;   // staging: 16 rows per 256-thr pass

  // stage Bt (columns, prescaled)
  for (int it = 0; it < 8; it++) {
    int r = sr + it * 16;
    *(bf16x8*)&Bt[r * 136 + sseg * 8] =
        *(const bf16x8*)&nxe[(ct * 128 + r) * 128 + sseg * 8];
  }
  // tile list (skip diagonal class block — cancels analytically)
  int tiles[8], nt = 0;
  for (int c8 = 0; c8 < 8; c8++) {
    int row0 = rs * 1024 + c8 * 128;
    if (row0 != ct * 128) tiles[nt++] = row0;
  }
  bf16x8 pre[8];
  for (int it = 0; it < 8; it++)
    pre[it] = *(const bf16x8*)&nxb[(tiles[0] + sr + it * 16) * 128 + sseg * 8];

  float colacc[8];
  for (int j = 0; j < 8; j++) colacc[j] = 0.0f;

  for (int ti = 0; ti < nt; ti++) {
    for (int it = 0; it < 8; it++)
      *(bf16x8*)&At[(sr + it * 16) * 136 + sseg * 8] = pre[it];
    __syncthreads();
    if (ti + 1 < nt) {
      int row0 = tiles[ti + 1];
      for (int it = 0; it < 8; it++)
        pre[it] = *(const bf16x8*)&nxb[(row0 + sr + it * 16) * 128 + sseg * 8];
    }
    f32x4 acc[2][8];
    f32x4 zero = {0.0f, 0.0f, 0.0f, 0.0f};
    for (int i = 0; i < 2; i++)
      for (int j = 0; j < 8; j++) acc[i][j] = zero;
    for (int kc = 0; kc < 4; kc++) {
      bf16x8 a0 = *(const bf16x8*)&At[(w * 32 + lrow) * 136 + kc * 32 + quad * 8];
      bf16x8 a1 = *(const bf16x8*)&At[(w * 32 + 16 + lrow) * 136 + kc * 32 + quad * 8];
      for (int j = 0; j < 8; j++) {
        bf16x8 b = *(const bf16x8*)&Bt[(j * 16 + lrow) * 136 + kc * 32 + quad * 8];
        acc[0][j] = __builtin_amdgcn_mfma_f32_16x16x32_bf16(a0, b, acc[0][j], 0, 0, 0);
        acc[1][j] = __builtin_amdgcn_mfma_f32_16x16x32_bf16(a1, b, acc[1][j], 0, 0, 0);
      }
    }
    for (int i = 0; i < 2; i++)
      for (int j = 0; j < 8; j++)
        for (int r = 0; r < 4; r++)
          colacc[j] += exp2f(acc[i][j][r]);
    __syncthreads();
  }

  for (int j = 0; j < 8; j++) {
    float v = colacc[j];
    v += __shfl_xor(v, 16, 64);
    v += __shfl_xor(v, 32, 64);
    if (lane < 16) colpart[w * 128 + j * 16 + lane] = v;
  }
  __syncthreads();
  if (t < 128) {
    float s = colpart[t] + colpart[128 + t] + colpart[256 + t] + colpart[384 + t];
    cspart[rs * 8192 + ct * 128 + t] = s;
  }
}

// ---------------------------------------------------------------------------
// 4. fused proto + instance loss + last-block finalize. grid (64, 2), 256 thr.
//    Per class: 64 A-rows (this half), all 128 cols via nxe, 64 protos via nprE.
// ---------------------------------------------------------------------------
__global__ __launch_bounds__(256) void k_fused(const __bf16* __restrict__ nxb,
                                               const __bf16* __restrict__ nxe,
                                               const __bf16* __restrict__ nprE,
                                               const float* __restrict__ cspart,
                                               float* __restrict__ accs,
                                               float* __restrict__ out) {
  __shared__ __bf16 Xt[64 * 136];
  __shared__ __bf16 XtE[128 * 136];
  __shared__ __bf16 PtE[64 * 136];
  __shared__ float  negl[128];
  const int t = threadIdx.x, cls = blockIdx.x, half = blockIdx.y;
  const int sr = t >> 4, sseg = t & 15;

  for (int it = 0; it < 4; it++) {
    int r = sr + it * 16;
    *(bf16x8*)&Xt[r * 136 + sseg * 8] =
        *(const bf16x8*)&nxb[(cls * 128 + half * 64 + r) * 128 + sseg * 8];
    *(bf16x8*)&PtE[r * 136 + sseg * 8] =
        *(const bf16x8*)&nprE[r * 128 + sseg * 8];
  }
  for (int it = 0; it < 8; it++) {
    int r = sr + it * 16;
    *(bf16x8*)&XtE[r * 136 + sseg * 8] =
        *(const bf16x8*)&nxe[(cls * 128 + r) * 128 + sseg * 8];
  }
  if (t < 128) {
    float s = 0.0f;
    for (int s8 = 0; s8 < 8; s8++) s += cspart[s8 * 8192 + cls * 128 + t];
    negl[t] = s;
  }
  __syncthreads();

  const int wv = t >> 6, lane = t & 63;
  const int quad = lane >> 4, lrow = lane & 15;
  f32x4 zero = {0.f, 0.f, 0.f, 0.f};
  f32x4 acc_i[8], acc_p[4];
  for (int j = 0; j < 8; j++) acc_i[j] = zero;
  for (int j = 0; j < 4; j++) acc_p[j] = zero;

  for (int kc = 0; kc < 4; kc++) {
    bf16x8 a = *(const bf16x8*)&Xt[(wv * 16 + lrow) * 136 + kc * 32 + quad * 8];
    for (int j = 0; j < 8; j++) {
      bf16x8 b = *(const bf16x8*)&XtE[(j * 16 + lrow) * 136 + kc * 32 + quad * 8];
      acc_i[j] = __builtin_amdgcn_mfma_f32_16x16x32_bf16(a, b, acc_i[j], 0, 0, 0);
    }
    for (int j = 0; j < 4; j++) {
      bf16x8 b = *(const bf16x8*)&PtE[(j * 16 + lrow) * 136 + kc * 32 + quad * 8];
      acc_p[j] = __builtin_amdgcn_mfma_f32_16x16x32_bf16(a, b, acc_p[j], 0, 0, 0);
    }
  }

  // proto term: log(sum_k exp2(acc_p)) - acc_pos*ln2
  float wacc0 = 0.0f;
  for (int r = 0; r < 4; r++) {
    float tot = 0.0f;
    for (int j = 0; j < 4; j++) tot += exp2f(acc_p[j][r]);
    tot += __shfl_xor(tot, 1, 64);
    tot += __shfl_xor(tot, 2, 64);
    tot += __shfl_xor(tot, 4, 64);
    tot += __shfl_xor(tot, 8, 64);
    if (lrow == 0) wacc0 += logf(tot);
  }
  {
    const int jc = cls >> 4, colc = cls & 15;
    if (lrow == colc) {
      float sd = 0.0f;
      switch (jc) {
        case 0: for (int r = 0; r < 4; r++) sd += acc_p[0][r]; break;
        case 1: for (int r = 0; r < 4; r++) sd += acc_p[1][r]; break;
        case 2: for (int r = 0; r < 4; r++) sd += acc_p[2][r]; break;
        default: for (int r = 0; r < 4; r++) sd += acc_p[3][r]; break;
      }
      wacc0 -= sd * LN2F;
    }
  }
  // instance term
  float wacc1 = 0.0f;
  for (int j = 0; j < 8; j++) {
    float ng = negl[j * 16 + lrow];
    for (int r = 0; r < 4; r++)
      wacc1 += log1pf(ng * exp2f(-acc_i[j][r]));
  }
  for (int off = 32; off; off >>= 1) {
    wacc0 += __shfl_xor(wacc0, off, 64);
    wacc1 += __shfl_xor(wacc1, off, 64);
  }
  if (lane == 0) {
    atomicAdd(&accs[0], wacc0);
    atomicAdd(&accs[1], wacc1);
  }
  __syncthreads();
  if (t == 0) {
    __threadfence();
    unsigned int old = atomicAdd((unsigned int*)&accs[2], 1u);
    if (old == 127u) {
      __threadfence();
      float a0 = atomicAdd(&accs[0], 0.0f);
      float a1 = atomicAdd(&accs[1], 0.0f);
      out[0] = a0 * (1.0f / 524288.0f) + a1 * (1.0f / 67108864.0f);
    }
  }
}

// ---------------------------------------------------------------------------
extern "C" void kernel_launch(void* const* d_in, const int* in_sizes, int n_in,
                              void* d_out, int out_size, void* d_ws, size_t ws_size,
                              hipStream_t stream) {
  const float* e  = (const float*)d_in[0];   // embeds [64,128,768]
  const float* w  = (const float*)d_in[1];   // head_w [128,768]
  const float* hb = (const float*)d_in[2];   // head_b [128]
  const float* pr = (const float*)d_in[3];   // proto  [64,128]
  char* ws = (char*)d_ws;
  __bf16* nxb    = (__bf16*)ws;                              // 2 MB
  __bf16* nxe    = (__bf16*)(ws + (2 << 20));                // 2 MB
  __bf16* wb     = (__bf16*)(ws + (4 << 20));                // 192 KB
  __bf16* nprE   = (__bf16*)(ws + (4 << 20) + (256 << 10));  // 16 KB
  float*  cspart = (float*)(ws + (4 << 20) + (512 << 10));   // 256 KB
  float*  accs   = (float*)(ws + (5 << 20));                 // 16 B
  float*  out    = (float*)d_out;

  k_prep<<<128, 256, 0, stream>>>(w, pr, wb, nprE, accs);
  k_headnorm<<<256, 256, 0, stream>>>(e, wb, hb, nxb, nxe);
  k_colsum<<<dim3(64, 8), 256, 0, stream>>>(nxb, nxe, cspart);
  k_fused<<<dim3(64, 2), 256, 0, stream>>>(nxb, nxe, nprE, cspart, accs, out);
}

// Round 4
// 142.014 us; speedup vs baseline: 1.4797x; 1.0707x over previous
//
#include <hip/hip_runtime.h>
#include <math.h>

#define SCALE_INV 20.0f
#define EXPK 28.853900817779268f   // SCALE_INV * log2(e)
#define LN2F 0.6931471805599453f   // SCALE_INV / EXPK

typedef __bf16 bf16x8 __attribute__((ext_vector_type(8)));
typedef float  f32x4  __attribute__((ext_vector_type(4)));

// ---------------------------------------------------------------------------
// 1. fused head GEMM + bias + l2norm -> nxb, nxe. grid 256 x 256 thr.
//    32 rows/block, K-chunks of 64, fp32 w convert-on-stage (round-2 proven).
//    Also zeroes cspart (32 floats/block) and accs (block 0) for later passes.
// ---------------------------------------------------------------------------
__global__ __launch_bounds__(256) void k_headnorm(const float* __restrict__ e,
                                                  const float* __restrict__ w,
                                                  const float* __restrict__ hb,
                                                  __bf16* __restrict__ nxb,
                                                  __bf16* __restrict__ nxe,
                                                  float* __restrict__ cspart,
                                                  float* __restrict__ accs) {
  __shared__ __bf16 Ab[32 * 72];    // 32 rows x 64 k
  __shared__ __bf16 Bb[128 * 72];   // 128 h  x 64 k
  __shared__ float  xt[32 * 132];   // output tile for norm
  __shared__ float  hbl[128];
  const int t  = threadIdx.x;
  const int rt = blockIdx.x;
  if (t < 128) hbl[t] = hb[t];
  if (t < 32) cspart[rt * 32 + t] = 0.0f;          // zero neg-accumulator
  if (rt == 0 && t >= 128 && t < 132) accs[t - 128] = 0.0f;

  const int arow = t >> 3, akoff = (t & 7) * 8;   // A: 8 floats/thread
  const int brow = t >> 1, bkoff = (t & 1) * 32;  // B: 32 floats/thread
  float4 ar[2], br[8];
  {
    const float* p = &e[(rt * 32 + arow) * 768 + akoff];
    ar[0] = *(const float4*)p; ar[1] = *(const float4*)(p + 4);
    const float* q = &w[brow * 768 + bkoff];
    for (int i = 0; i < 8; i++) br[i] = *(const float4*)(q + 4 * i);
  }

  const int wv = t >> 6, lane = t & 63;
  const int quad = lane >> 4, lrow = lane & 15;
  const int rb = wv & 1, cb = wv >> 1;
  f32x4 acc[4];
  f32x4 zero = {0.f, 0.f, 0.f, 0.f};
  for (int j = 0; j < 4; j++) acc[j] = zero;

  for (int it = 0; it < 12; it++) {
    {
      __bf16 ta[8];
      const float* f = (const float*)ar;
      for (int i = 0; i < 8; i++) ta[i] = (__bf16)f[i];
      *(bf16x8*)&Ab[arow * 72 + akoff] = *(bf16x8*)ta;
      const float* g = (const float*)br;
      for (int seg = 0; seg < 4; seg++) {
        __bf16 tb[8];
        for (int i = 0; i < 8; i++) tb[i] = (__bf16)g[seg * 8 + i];
        *(bf16x8*)&Bb[brow * 72 + bkoff + seg * 8] = *(bf16x8*)tb;
      }
    }
    __syncthreads();
    if (it < 11) {
      int kb = (it + 1) * 64;
      const float* p = &e[(rt * 32 + arow) * 768 + kb + akoff];
      ar[0] = *(const float4*)p; ar[1] = *(const float4*)(p + 4);
      const float* q = &w[brow * 768 + kb + bkoff];
      for (int i = 0; i < 8; i++) br[i] = *(const float4*)(q + 4 * i);
    }
    for (int kc = 0; kc < 2; kc++) {
      bf16x8 a = *(const bf16x8*)&Ab[(rb * 16 + lrow) * 72 + kc * 32 + quad * 8];
      for (int j = 0; j < 4; j++) {
        bf16x8 b = *(const bf16x8*)&Bb[(cb * 64 + j * 16 + lrow) * 72 + kc * 32 + quad * 8];
        acc[j] = __builtin_amdgcn_mfma_f32_16x16x32_bf16(a, b, acc[j], 0, 0, 0);
      }
    }
    __syncthreads();
  }

  for (int j = 0; j < 4; j++)
    for (int r = 0; r < 4; r++) {
      int row = rb * 16 + quad * 4 + r;
      int col = cb * 64 + j * 16 + lrow;
      xt[row * 132 + col] = acc[j][r] + hbl[col];
    }
  __syncthreads();
  {
    int row = t >> 3, c0 = (t & 7) * 16;
    float v[16];
    float s = 0.0f;
    for (int i = 0; i < 4; i++) {
      float4 f = *(const float4*)&xt[row * 132 + c0 + i * 4];
      v[i * 4] = f.x; v[i * 4 + 1] = f.y; v[i * 4 + 2] = f.z; v[i * 4 + 3] = f.w;
    }
    for (int i = 0; i < 16; i++) s += v[i] * v[i];
    s += __shfl_xor(s, 1, 64);
    s += __shfl_xor(s, 2, 64);
    s += __shfl_xor(s, 4, 64);
    float inv = 1.0f / fmaxf(sqrtf(s), 1e-12f);
    __bf16 o[16], oe[16];
    for (int i = 0; i < 16; i++) {
      float nv = v[i] * inv;
      o[i]  = (__bf16)nv;
      oe[i] = (__bf16)(nv * EXPK);
    }
    __bf16* dst = &nxb[(rt * 32 + row) * 128 + c0];
    *(bf16x8*)dst       = *(bf16x8*)o;
    *(bf16x8*)(dst + 8) = *(bf16x8*)(o + 8);
    __bf16* dse = &nxe[(rt * 32 + row) * 128 + c0];
    *(bf16x8*)dse       = *(bf16x8*)oe;
    *(bf16x8*)(dse + 8) = *(bf16x8*)(oe + 8);
  }
}

// ---------------------------------------------------------------------------
// 2. symmetric off-class colsum. grid (64, 8), 256 thr.
//    Each unordered class pair computed ONCE: block (cj, rs) handles partner
//    classes ci = (cj + m) % 64 for m in [4rs+1, 4rs+4] (m=32 only if cj<32)
//    -> exactly 2016 tiles. exp'd tile reduced both ways:
//    col-sums -> neg[class cj], row-sums -> neg[class ci] (S is symmetric).
// ---------------------------------------------------------------------------
__global__ __launch_bounds__(256) void k_colsum(const __bf16* __restrict__ nxb,
                                                const __bf16* __restrict__ nxe,
                                                float* __restrict__ cspart) {
  __shared__ __bf16 At[128 * 136];
  __shared__ __bf16 Bt[128 * 136];
  __shared__ float  colpart[4 * 128];
  const int t    = threadIdx.x;
  const int cj   = blockIdx.x;
  const int rs   = blockIdx.y;
  const int w    = t >> 6, lane = t & 63;
  const int quad = lane >> 4, lrow = lane & 15;
  const int sr   = t >> 4, sseg = t & 15;

  // stage B = prescaled columns of class cj
  for (int it = 0; it < 8; it++) {
    int r = sr + it * 16;
    *(bf16x8*)&Bt[r * 136 + sseg * 8] =
        *(const bf16x8*)&nxe[(cj * 128 + r) * 128 + sseg * 8];
  }
  // partner-tile list
  int tiles[4], nt = 0;
  for (int mm = 0; mm < 4; mm++) {
    int m = rs * 4 + 1 + mm;
    if (m < 32 || cj < 32) tiles[nt++] = (cj + m) & 63;
  }
  bf16x8 pre[8];
  for (int it = 0; it < 8; it++)
    pre[it] = *(const bf16x8*)&nxb[(tiles[0] * 128 + sr + it * 16) * 128 + sseg * 8];

  float colacc[8];
  for (int j = 0; j < 8; j++) colacc[j] = 0.0f;

  for (int ti = 0; ti < nt; ti++) {
    const int ci = tiles[ti];
    for (int it = 0; it < 8; it++)
      *(bf16x8*)&At[(sr + it * 16) * 136 + sseg * 8] = pre[it];
    __syncthreads();
    if (ti + 1 < nt) {
      int cn = tiles[ti + 1];
      for (int it = 0; it < 8; it++)
        pre[it] = *(const bf16x8*)&nxb[(cn * 128 + sr + it * 16) * 128 + sseg * 8];
    }
    f32x4 acc[2][8];
    f32x4 zero = {0.0f, 0.0f, 0.0f, 0.0f};
    for (int i = 0; i < 2; i++)
      for (int j = 0; j < 8; j++) acc[i][j] = zero;
    for (int kc = 0; kc < 4; kc++) {
      bf16x8 a0 = *(const bf16x8*)&At[(w * 32 + lrow) * 136 + kc * 32 + quad * 8];
      bf16x8 a1 = *(const bf16x8*)&At[(w * 32 + 16 + lrow) * 136 + kc * 32 + quad * 8];
      for (int j = 0; j < 8; j++) {
        bf16x8 b = *(const bf16x8*)&Bt[(j * 16 + lrow) * 136 + kc * 32 + quad * 8];
        acc[0][j] = __builtin_amdgcn_mfma_f32_16x16x32_bf16(a0, b, acc[0][j], 0, 0, 0);
        acc[1][j] = __builtin_amdgcn_mfma_f32_16x16x32_bf16(a1, b, acc[1][j], 0, 0, 0);
      }
    }
    // exp once; accumulate col sums (for cj) and row sums (for ci)
    float rsum[2][4];
    for (int i = 0; i < 2; i++)
      for (int r = 0; r < 4; r++) rsum[i][r] = 0.0f;
    for (int i = 0; i < 2; i++)
      for (int j = 0; j < 8; j++)
        for (int r = 0; r < 4; r++) {
          float ev = exp2f(acc[i][j][r]);
          colacc[j]  += ev;
          rsum[i][r] += ev;
        }
    for (int i = 0; i < 2; i++)
      for (int r = 0; r < 4; r++) {
        float v = rsum[i][r];
        v += __shfl_xor(v, 1, 64);
        v += __shfl_xor(v, 2, 64);
        v += __shfl_xor(v, 4, 64);
        v += __shfl_xor(v, 8, 64);
        if (lrow == 0)
          atomicAdd(&cspart[ci * 128 + w * 32 + i * 16 + quad * 4 + r], v);
      }
    __syncthreads();
  }

  // col-sum reduction (over quads, then waves), one atomic per column
  for (int j = 0; j < 8; j++) {
    float v = colacc[j];
    v += __shfl_xor(v, 16, 64);
    v += __shfl_xor(v, 32, 64);
    if (lane < 16) colpart[w * 128 + j * 16 + lane] = v;
  }
  __syncthreads();
  if (t < 128) {
    float s = colpart[t] + colpart[128 + t] + colpart[256 + t] + colpart[384 + t];
    atomicAdd(&cspart[cj * 128 + t], s);
  }
}

// ---------------------------------------------------------------------------
// 3. fused proto + instance loss + finalize. grid (64, 2), 256 thr.
//    Proto l2norm computed in-LDS (no global round-trip, kills k_prep).
// ---------------------------------------------------------------------------
__global__ __launch_bounds__(256) void k_fused(const __bf16* __restrict__ nxb,
                                               const __bf16* __restrict__ nxe,
                                               const float* __restrict__ proto,
                                               const float* __restrict__ cspart,
                                               float* __restrict__ accs,
                                               float* __restrict__ out) {
  __shared__ __bf16 Xt[64 * 136];
  __shared__ __bf16 XtE[128 * 136];
  __shared__ __bf16 PtE[64 * 136];
  __shared__ float  negl[128];
  const int t = threadIdx.x, cls = blockIdx.x, half = blockIdx.y;
  const int sr = t >> 4, sseg = t & 15;

  // norm protos into PtE: 4 threads per row, 32 elems each
  {
    const int rw = t >> 2, part = t & 3;
    float v[32];
    float s = 0.0f;
    const float* p = &proto[rw * 128 + part * 32];
    for (int i = 0; i < 8; i++) {
      float4 f = *(const float4*)(p + 4 * i);
      v[i * 4] = f.x; v[i * 4 + 1] = f.y; v[i * 4 + 2] = f.z; v[i * 4 + 3] = f.w;
      s += f.x * f.x + f.y * f.y + f.z * f.z + f.w * f.w;
    }
    s += __shfl_xor(s, 1, 64);
    s += __shfl_xor(s, 2, 64);
    float inv = EXPK / fmaxf(sqrtf(s), 1e-12f);
    __bf16 o[32];
    for (int i = 0; i < 32; i++) o[i] = (__bf16)(v[i] * inv);
    __bf16* dst = &PtE[rw * 136 + part * 32];
    for (int i = 0; i < 4; i++) *(bf16x8*)(dst + i * 8) = *(bf16x8*)(o + i * 8);
  }
  for (int it = 0; it < 4; it++) {
    int r = sr + it * 16;
    *(bf16x8*)&Xt[r * 136 + sseg * 8] =
        *(const bf16x8*)&nxb[(cls * 128 + half * 64 + r) * 128 + sseg * 8];
  }
  for (int it = 0; it < 8; it++) {
    int r = sr + it * 16;
    *(bf16x8*)&XtE[r * 136 + sseg * 8] =
        *(const bf16x8*)&nxe[(cls * 128 + r) * 128 + sseg * 8];
  }
  if (t < 128) negl[t] = cspart[cls * 128 + t];
  __syncthreads();

  const int wv = t >> 6, lane = t & 63;
  const int quad = lane >> 4, lrow = lane & 15;
  f32x4 zero = {0.f, 0.f, 0.f, 0.f};
  f32x4 acc_i[8], acc_p[4];
  for (int j = 0; j < 8; j++) acc_i[j] = zero;
  for (int j = 0; j < 4; j++) acc_p[j] = zero;

  for (int kc = 0; kc < 4; kc++) {
    bf16x8 a = *(const bf16x8*)&Xt[(wv * 16 + lrow) * 136 + kc * 32 + quad * 8];
    for (int j = 0; j < 8; j++) {
      bf16x8 b = *(const bf16x8*)&XtE[(j * 16 + lrow) * 136 + kc * 32 + quad * 8];
      acc_i[j] = __builtin_amdgcn_mfma_f32_16x16x32_bf16(a, b, acc_i[j], 0, 0, 0);
    }
    for (int j = 0; j < 4; j++) {
      bf16x8 b = *(const bf16x8*)&PtE[(j * 16 + lrow) * 136 + kc * 32 + quad * 8];
      acc_p[j] = __builtin_amdgcn_mfma_f32_16x16x32_bf16(a, b, acc_p[j], 0, 0, 0);
    }
  }

  // proto term
  float wacc0 = 0.0f;
  for (int r = 0; r < 4; r++) {
    float tot = 0.0f;
    for (int j = 0; j < 4; j++) tot += exp2f(acc_p[j][r]);
    tot += __shfl_xor(tot, 1, 64);
    tot += __shfl_xor(tot, 2, 64);
    tot += __shfl_xor(tot, 4, 64);
    tot += __shfl_xor(tot, 8, 64);
    if (lrow == 0) wacc0 += logf(tot);
  }
  {
    const int jc = cls >> 4, colc = cls & 15;
    if (lrow == colc) {
      float sd = 0.0f;
      switch (jc) {
        case 0: for (int r = 0; r < 4; r++) sd += acc_p[0][r]; break;
        case 1: for (int r = 0; r < 4; r++) sd += acc_p[1][r]; break;
        case 2: for (int r = 0; r < 4; r++) sd += acc_p[2][r]; break;
        default: for (int r = 0; r < 4; r++) sd += acc_p[3][r]; break;
      }
      wacc0 -= sd * LN2F;
    }
  }
  // instance term
  float wacc1 = 0.0f;
  for (int j = 0; j < 8; j++) {
    float ng = negl[j * 16 + lrow];
    for (int r = 0; r < 4; r++)
      wacc1 += log1pf(ng * exp2f(-acc_i[j][r]));
  }
  for (int off = 32; off; off >>= 1) {
    wacc0 += __shfl_xor(wacc0, off, 64);
    wacc1 += __shfl_xor(wacc1, off, 64);
  }
  if (lane == 0) {
    atomicAdd(&accs[0], wacc0);
    atomicAdd(&accs[1], wacc1);
  }
  __syncthreads();
  if (t == 0) {
    __threadfence();
    unsigned int old = atomicAdd((unsigned int*)&accs[2], 1u);
    if (old == 127u) {
      __threadfence();
      float a0 = atomicAdd(&accs[0], 0.0f);
      float a1 = atomicAdd(&accs[1], 0.0f);
      out[0] = a0 * (1.0f / 524288.0f) + a1 * (1.0f / 67108864.0f);
    }
  }
}

// ---------------------------------------------------------------------------
extern "C" void kernel_launch(void* const* d_in, const int* in_sizes, int n_in,
                              void* d_out, int out_size, void* d_ws, size_t ws_size,
                              hipStream_t stream) {
  const float* e  = (const float*)d_in[0];   // embeds [64,128,768]
  const float* w  = (const float*)d_in[1];   // head_w [128,768]
  const float* hb = (const float*)d_in[2];   // head_b [128]
  const float* pr = (const float*)d_in[3];   // proto  [64,128]
  char* ws = (char*)d_ws;
  __bf16* nxb    = (__bf16*)ws;                        // 2 MB
  __bf16* nxe    = (__bf16*)(ws + (2 << 20));          // 2 MB
  float*  cspart = (float*)(ws + (4 << 20));           // 32 KB
  float*  accs   = (float*)(ws + (4 << 20) + (64 << 10));  // 16 B
  float*  out    = (float*)d_out;

  k_headnorm<<<256, 256, 0, stream>>>(e, w, hb, nxb, nxe, cspart, accs);
  k_colsum<<<dim3(64, 8), 256, 0, stream>>>(nxb, nxe, cspart);
  k_fused<<<dim3(64, 2), 256, 0, stream>>>(nxb, nxe, pr, cspart, accs, out);
}